// Round 1
// baseline (196.434 us; speedup 1.0000x reference)
//
#include <hip/hip_runtime.h>

// channel_attention: the attention branch is mathematically the identity
// (einsum 'bdct,bdcm->bdct' sums softmax over m -> multiplies x by 1.0).
// Output = swap( LN_c( swap(x) @ pW.T + pb ) ) -- fused matvec + LayerNorm.

#define CC   64     // channels
#define TT   3000   // time
#define TILE 256    // t-values per block (one thread per t)
#define NT   12     // ceil(TT / TILE)

__global__ __launch_bounds__(TILE) void fused_proj_ln(
    const float* __restrict__ x,      // [BD, CC, TT]
    const float* __restrict__ pW,     // [CC, CC]
    const float* __restrict__ pb,     // [CC]
    const float* __restrict__ pg,     // [CC]
    const float* __restrict__ pbeta,  // [CC]
    float* __restrict__ out)          // [BD, CC, TT]
{
    // per-thread y storage (runtime-indexed -> LDS, not scratch).
    // ylds[co][tid]: lanes hit consecutive banks -> free 2-way aliasing.
    __shared__ float ylds[CC][TILE];

    const int bd   = blockIdx.x / NT;
    const int tile = blockIdx.x - bd * NT;
    const int tid  = threadIdx.x;
    const int t    = tile * TILE + tid;
    const bool active = (t < TT);

    const size_t base = (size_t)bd * (CC * TT) + (size_t)t;

    // Load this thread's 64-channel column of x (coalesced: lane i -> t+i).
    float xv[CC];
    if (active) {
#pragma unroll
        for (int c = 0; c < CC; ++c) xv[c] = x[base + (size_t)c * TT];
    } else {
#pragma unroll
        for (int c = 0; c < CC; ++c) xv[c] = 0.0f;
    }

    // y[co] = pb[co] + sum_k pW[co,k] * x[k]; accumulate mean / meansq on the fly.
    // pW/pb indices are block-uniform -> scalar loads, FMAs use SGPR operand.
    float sum = 0.0f, sumsq = 0.0f;
    for (int co = 0; co < CC; ++co) {
        float acc = pb[co];
        const float* __restrict__ wrow = pW + co * CC;
#pragma unroll
        for (int k = 0; k < CC; ++k) acc = fmaf(wrow[k], xv[k], acc);
        ylds[co][tid] = acc;   // own column only; no barrier needed
        sum   += acc;
        sumsq += acc * acc;
    }

    const float mu   = sum * (1.0f / CC);
    const float var  = sumsq * (1.0f / CC) - mu * mu;
    const float rstd = rsqrtf(var + 1e-5f);

    if (active) {
        for (int co = 0; co < CC; ++co) {
            const float yv = ylds[co][tid];
            out[base + (size_t)co * TT] = (yv - mu) * rstd * pg[co] + pbeta[co];
        }
    }
}

extern "C" void kernel_launch(void* const* d_in, const int* in_sizes, int n_in,
                              void* d_out, int out_size, void* d_ws, size_t ws_size,
                              hipStream_t stream) {
    // setup_inputs order: x, qW, qb, qg, qbeta, kW, kb, kg, kbeta, pW, pb, pg, pbeta
    const float* x     = (const float*)d_in[0];
    const float* pW    = (const float*)d_in[9];
    const float* pb    = (const float*)d_in[10];
    const float* pg    = (const float*)d_in[11];
    const float* pbeta = (const float*)d_in[12];
    float* out = (float*)d_out;

    const int BD = 32 * 8;               // B * D
    dim3 grid(BD * NT);                  // 3072 blocks
    dim3 block(TILE);
    fused_proj_ln<<<grid, block, 0, stream>>>(x, pW, pb, pg, pbeta, out);
}

// Round 2
// 182.000 us; speedup vs baseline: 1.0793x; 1.0793x over previous
//
#include <hip/hip_runtime.h>

// channel_attention: the attention branch is mathematically the identity
// (einsum 'bdct,bdcm->bdct' sums softmax over m -> multiplies x by 1.0).
// Output = swap( LN_c( swap(x) @ pW.T + pb ) ) -- fused matvec + LayerNorm.
//
// R1: ILP-8 matvec (8 independent FMA chains) + TILE=128 (32 KB LDS ->
// 5 blocks/CU = 10 waves/CU vs 8 before). Latency-bound fix; target ~62 us
// memory floor.

#define CC   64     // channels
#define TT   3000   // time
#define TILE 128    // t-values per block (one thread per t)
#define NT   24     // ceil(TT / TILE)
#define COG  8      // co-group size (independent accumulators)

__global__ __launch_bounds__(TILE) void fused_proj_ln(
    const float* __restrict__ x,      // [BD, CC, TT]
    const float* __restrict__ pW,     // [CC, CC]
    const float* __restrict__ pb,     // [CC]
    const float* __restrict__ pg,     // [CC]
    const float* __restrict__ pbeta,  // [CC]
    float* __restrict__ out)          // [BD, CC, TT]
{
    // per-thread y storage; ylds[co][tid]: lanes -> consecutive banks (free).
    __shared__ float ylds[CC][TILE];

    const int bd   = blockIdx.x / NT;
    const int tile = blockIdx.x - bd * NT;
    const int tid  = threadIdx.x;
    const int t    = tile * TILE + tid;
    const bool active = (t < TT);

    const size_t base = (size_t)bd * (CC * TT) + (size_t)t;

    // Load this thread's 64-channel column of x (coalesced: lane i -> t+i).
    float xv[CC];
#pragma unroll
    for (int c = 0; c < CC; ++c)
        xv[c] = active ? x[base + (size_t)c * TT] : 0.0f;

    // y[co] = pb[co] + sum_k pW[co,k] * x[k]; 8 rows at a time -> ILP 8.
    // Weight/bias indices are block-uniform -> s_load into SGPRs; the 512
    // FMAs per group give the scheduler room to prefetch the next chunk.
    float sum = 0.0f, sumsq = 0.0f;
    for (int co = 0; co < CC; co += COG) {
        float acc[COG];
#pragma unroll
        for (int j = 0; j < COG; ++j) acc[j] = pb[co + j];
#pragma unroll
        for (int k = 0; k < CC; ++k) {
            const float xk = xv[k];
#pragma unroll
            for (int j = 0; j < COG; ++j)
                acc[j] = fmaf(pW[(co + j) * CC + k], xk, acc[j]);
        }
#pragma unroll
        for (int j = 0; j < COG; ++j) {
            ylds[co + j][tid] = acc[j];   // own column only; no barrier needed
            sum   += acc[j];
            sumsq += acc[j] * acc[j];
        }
    }

    const float mu   = sum * (1.0f / CC);
    const float var  = sumsq * (1.0f / CC) - mu * mu;
    const float rstd = rsqrtf(var + 1e-5f);

    if (active) {
#pragma unroll 8
        for (int co = 0; co < CC; ++co) {
            const float yv = ylds[co][tid];
            out[base + (size_t)co * TT] = (yv - mu) * rstd * pg[co] + pbeta[co];
        }
    }
}

extern "C" void kernel_launch(void* const* d_in, const int* in_sizes, int n_in,
                              void* d_out, int out_size, void* d_ws, size_t ws_size,
                              hipStream_t stream) {
    // setup_inputs order: x, qW, qb, qg, qbeta, kW, kb, kg, kbeta, pW, pb, pg, pbeta
    const float* x     = (const float*)d_in[0];
    const float* pW    = (const float*)d_in[9];
    const float* pb    = (const float*)d_in[10];
    const float* pg    = (const float*)d_in[11];
    const float* pbeta = (const float*)d_in[12];
    float* out = (float*)d_out;

    const int BD = 32 * 8;               // B * D
    dim3 grid(BD * NT);                  // 6144 blocks
    dim3 block(TILE);
    fused_proj_ln<<<grid, block, 0, stream>>>(x, pW, pb, pg, pbeta, out);
}

// Round 3
// 118.120 us; speedup vs baseline: 1.6630x; 1.5408x over previous
//
#include <hip/hip_runtime.h>

// channel_attention: the attention branch is mathematically the identity
// (einsum 'bdct,bdcm->bdct' sums softmax over m -> multiplies x by 1.0).
// Output = swap( LN_c( swap(x) @ pW.T + pb ) ) -- fused matvec + LayerNorm.
//
// R2: outer-product matvec, y[64] in VGPRs (static indexing), NO LDS, no
// xv[] array -- x consumed streaming. Weights pre-transposed into d_ws so
// the k-th step reads a contiguous row Wt[k][0..63] (uniform -> s_load).
// Register ~90 -> 5+ waves/SIMD; target the ~62 us memory floor.

#define CC  64
#define TT  3000
#define TPB 256
#define NT  12   // ceil(TT / TPB)

__global__ void transpose_w(const float* __restrict__ pW, float* __restrict__ Wt) {
    // Wt[k*CC + j] = pW[j*CC + k]  (so y[j] += Wt[k][j] * x[k])
    int i = blockIdx.x * blockDim.x + threadIdx.x;
    if (i < CC * CC) {
        int k = i >> 6;
        int j = i & 63;
        Wt[i] = pW[j * CC + k];
    }
}

__global__ __launch_bounds__(TPB) void fused_proj_ln(
    const float* __restrict__ x,      // [BD, CC, TT]
    const float* __restrict__ Wt,     // [CC, CC] transposed weights
    const float* __restrict__ pb,     // [CC]
    const float* __restrict__ pg,     // [CC]
    const float* __restrict__ pbeta,  // [CC]
    float* __restrict__ out)          // [BD, CC, TT]
{
    const int bd   = blockIdx.x / NT;
    const int tile = blockIdx.x - bd * NT;
    const int tid  = threadIdx.x;
    const int t    = tile * TPB + tid;
    const bool active = (t < TT);
    const int tc   = active ? t : (TT - 1);   // clamp: tail threads read safely

    const float* __restrict__ xp = x + (size_t)bd * (CC * TT) + tc;

    // y lives entirely in VGPRs (all indices compile-time).
    float y[CC];
#pragma unroll
    for (int j = 0; j < CC; ++j) y[j] = pb[j];

    // Outer-product accumulation: stream x one element per k, 64 FMAs each.
    // Wt row address is block-uniform -> scalar loads -> v_fmac(sgpr, vgpr).
#pragma unroll 4
    for (int k = 0; k < CC; ++k) {
        const float xk = xp[(size_t)k * TT];
        const float* __restrict__ wr = Wt + k * CC;
#pragma unroll
        for (int j = 0; j < CC; ++j) y[j] = fmaf(wr[j], xk, y[j]);
    }

    float sum = 0.0f, sumsq = 0.0f;
#pragma unroll
    for (int j = 0; j < CC; ++j) { sum += y[j]; sumsq = fmaf(y[j], y[j], sumsq); }
    const float mu   = sum * (1.0f / CC);
    const float rstd = rsqrtf(sumsq * (1.0f / CC) - mu * mu + 1e-5f);

    if (active) {
        float* __restrict__ op = out + (size_t)bd * (CC * TT) + t;
#pragma unroll
        for (int j = 0; j < CC; ++j)
            op[(size_t)j * TT] = (y[j] - mu) * rstd * pg[j] + pbeta[j];
    }
}

extern "C" void kernel_launch(void* const* d_in, const int* in_sizes, int n_in,
                              void* d_out, int out_size, void* d_ws, size_t ws_size,
                              hipStream_t stream) {
    // setup_inputs order: x, qW, qb, qg, qbeta, kW, kb, kg, kbeta, pW, pb, pg, pbeta
    const float* x     = (const float*)d_in[0];
    const float* pW    = (const float*)d_in[9];
    const float* pb    = (const float*)d_in[10];
    const float* pg    = (const float*)d_in[11];
    const float* pbeta = (const float*)d_in[12];
    float* out = (float*)d_out;
    float* Wt  = (float*)d_ws;   // 64*64*4 = 16 KB scratch

    transpose_w<<<(CC * CC + 255) / 256, 256, 0, stream>>>(pW, Wt);

    const int BD = 32 * 8;               // B * D
    dim3 grid(BD * NT);                  // 3072 blocks
    dim3 block(TPB);
    fused_proj_ln<<<grid, block, 0, stream>>>(x, Wt, pb, pg, pbeta, out);
}

// Round 4
// 105.166 us; speedup vs baseline: 1.8678x; 1.1232x over previous
//
#include <hip/hip_runtime.h>

// channel_attention: the attention branch is the identity (softmax over m
// sums to 1 in einsum 'bdct,bdcm->bdct'). Output = LN_c(pW @ x + pb) per
// (b,d,t) column.
//
// R3: MFMA formulation. C[co,t] = sum_c W[co,c] x[c,t] is a 64x64x768000
// bf16 GEMM: per wave, W lives in 8 A-frags (32 VGPR, loaded once from a
// pre-packed ws layout), 32 t-columns per wave, 8 mfma_32x32x16_bf16 each.
// LN epilogue on the measured C/D layout: col=lane&31,
// row=(reg&3)+8*(reg>>2)+4*(lane>>5); one shfl_xor(32) completes stats.
// A/B within-K permutation cancels (same (half,e)->c rule both sides).

#define CC    64
#define TT    3000
#define WT    32      // t-columns per wave
#define BTILE 128     // t per block (4 waves)
#define NTB   24      // ceil(TT / BTILE)

typedef __attribute__((ext_vector_type(8)))  short short8;
typedef __attribute__((ext_vector_type(16))) float f32x16;

static __device__ __forceinline__ short f2bf(float f) {
    // round-to-nearest-even f32 -> bf16 (inputs are finite)
    unsigned u = __builtin_bit_cast(unsigned, f);
    unsigned r = (u + 0x7FFFu + ((u >> 16) & 1u)) >> 16;
    return (short)r;
}

// ws layout: Wf = 4096 shorts (8 KB) at offset 0; Pf = 192 floats at 8192 B.
// Wf[((ct*4+kc)*64 + lane)*8 + e] = bf16(pW[co*CC + c]),
//   co = ct*32 + (lane&31), c = kc*16 + (lane>>5)*8 + e.
// Pf[a*64 + (ct*2+half)*16 + r] = {pb,pg,pbeta}[ct*32 + half*4 + (r&3) + 8*(r>>2)]
__global__ void pack_params(const float* __restrict__ pW,
                            const float* __restrict__ pb,
                            const float* __restrict__ pg,
                            const float* __restrict__ pbeta,
                            short* __restrict__ Wf, float* __restrict__ Pf)
{
    int i = blockIdx.x * 256 + threadIdx.x;
    if (i < 4096) {
        int e = i & 7, l = (i >> 3) & 63, f = i >> 9;
        int ct = f >> 2, kc = f & 3;
        int co = ct * 32 + (l & 31);
        int c  = kc * 16 + (l >> 5) * 8 + e;
        Wf[i] = f2bf(pW[co * CC + c]);
    } else if (i < 4096 + 192) {
        int j = i - 4096;
        int a = j >> 6, q = j & 63;
        int r = q & 15, half = (q >> 4) & 1, ct = q >> 5;
        int co = ct * 32 + half * 4 + (r & 3) + 8 * (r >> 2);
        const float* src = (a == 0) ? pb : (a == 1) ? pg : pbeta;
        Pf[j] = src[co];
    }
}

__global__ __launch_bounds__(256) void fused_mfma_ln(
    const float* __restrict__ x,    // [BD, CC, TT]
    const short* __restrict__ Wf,
    const float* __restrict__ Pf,
    float* __restrict__ out)        // [BD, CC, TT]
{
    const int tid  = threadIdx.x;
    const int lane = tid & 63;
    const int wid  = tid >> 6;
    const int bd   = blockIdx.x / NTB;
    const int tb   = blockIdx.x - bd * NTB;
    const int t0   = tb * BTILE + wid * WT;
    const int col  = lane & 31;
    const int half = lane >> 5;
    const int t    = t0 + col;
    const bool active = (t < TT);
    const int tc   = active ? t : (TT - 1);

    const float* __restrict__ xp = x + (size_t)bd * (CC * TT) + tc;

    // All of W, fragment-ordered, once per wave: 8 x 16B loads.
    short8 aW[2][4];
#pragma unroll
    for (int ct = 0; ct < 2; ++ct)
#pragma unroll
        for (int kc = 0; kc < 4; ++kc)
            aW[ct][kc] = ((const short8*)Wf)[(ct * 4 + kc) * 64 + lane];

    f32x16 acc[2];
#pragma unroll
    for (int r = 0; r < 16; ++r) { acc[0][r] = 0.0f; acc[1][r] = 0.0f; }

#pragma unroll
    for (int kc = 0; kc < 4; ++kc) {
        short8 bx;
#pragma unroll
        for (int e = 0; e < 8; ++e) {
            const int c = kc * 16 + half * 8 + e;
            bx[e] = f2bf(xp[(size_t)c * TT]);
        }
        acc[0] = __builtin_amdgcn_mfma_f32_32x32x16_bf16(aW[0][kc], bx, acc[0], 0, 0, 0);
        acc[1] = __builtin_amdgcn_mfma_f32_32x32x16_bf16(aW[1][kc], bx, acc[1], 0, 0, 0);
    }

    // bias (C-layout-packed) + LN stats
    float s = 0.0f, s2 = 0.0f;
#pragma unroll
    for (int ct = 0; ct < 2; ++ct) {
        const float4* pbv = (const float4*)(Pf + (ct * 2 + half) * 16);
#pragma unroll
        for (int q = 0; q < 4; ++q) {
            const float4 b4 = pbv[q];
            acc[ct][q * 4 + 0] += b4.x;
            acc[ct][q * 4 + 1] += b4.y;
            acc[ct][q * 4 + 2] += b4.z;
            acc[ct][q * 4 + 3] += b4.w;
        }
#pragma unroll
        for (int r = 0; r < 16; ++r) {
            const float v = acc[ct][r];
            s += v;
            s2 = fmaf(v, v, s2);
        }
    }
    s  += __shfl_xor(s, 32);
    s2 += __shfl_xor(s2, 32);
    const float mu   = s * (1.0f / CC);
    const float rstd = rsqrtf(s2 * (1.0f / CC) - mu * mu + 1e-5f);

    if (active) {
        float* __restrict__ op = out + (size_t)bd * (CC * TT) + t;
#pragma unroll
        for (int ct = 0; ct < 2; ++ct) {
            const float4* pgv = (const float4*)(Pf + 64  + (ct * 2 + half) * 16);
            const float4* pev = (const float4*)(Pf + 128 + (ct * 2 + half) * 16);
#pragma unroll
            for (int q = 0; q < 4; ++q) {
                const float4 g4 = pgv[q];
                const float4 e4 = pev[q];
                const float gg[4] = {g4.x, g4.y, g4.z, g4.w};
                const float ee[4] = {e4.x, e4.y, e4.z, e4.w};
#pragma unroll
                for (int j = 0; j < 4; ++j) {
                    const int r  = q * 4 + j;
                    const int co = ct * 32 + half * 4 + (r & 3) + 8 * (r >> 2);
                    op[(size_t)co * TT] = (acc[ct][r] - mu) * rstd * gg[j] + ee[j];
                }
            }
        }
    }
}

extern "C" void kernel_launch(void* const* d_in, const int* in_sizes, int n_in,
                              void* d_out, int out_size, void* d_ws, size_t ws_size,
                              hipStream_t stream) {
    // setup_inputs order: x, qW, qb, qg, qbeta, kW, kb, kg, kbeta, pW, pb, pg, pbeta
    const float* x     = (const float*)d_in[0];
    const float* pW    = (const float*)d_in[9];
    const float* pb    = (const float*)d_in[10];
    const float* pg    = (const float*)d_in[11];
    const float* pbeta = (const float*)d_in[12];
    float* out = (float*)d_out;

    short* Wf = (short*)d_ws;                          // 8 KB
    float* Pf = (float*)((char*)d_ws + 8192);          // 768 B

    pack_params<<<17, 256, 0, stream>>>(pW, pb, pg, pbeta, Wf, Pf);

    const int BD = 32 * 8;
    dim3 grid(BD * NTB);    // 6144 blocks
    dim3 block(256);
    fused_mfma_ln<<<grid, block, 0, stream>>>(x, Wf, Pf, out);
}